// Round 19
// baseline (161.935 us; speedup 1.0000x reference)
//
#include <hip/hip_runtime.h>
#include <cstdint>

typedef __attribute__((ext_vector_type(8))) short short8;
typedef __attribute__((ext_vector_type(4))) float f32x4;
typedef unsigned short ushort_t;

static constexpr int NN = 16384, FF = 256, GG = 64, EE = 131072, LL = 3;
static constexpr int HIDN = 512, IU = 32640, IN1 = 33408;
#define EPSV 1e-5f

__device__ inline unsigned short bf16r(float v) {
  unsigned u = __float_as_uint(v);
  u += 0x7FFFu + ((u >> 16) & 1u);
  return (unsigned short)(u >> 16);
}

// -------- k_pre: zero deg/cnt (0..64) + zero m1 (65..192) + zero out (193) +
//          pre-split conv W (194..961) ----------------------------------------------
__global__ __launch_bounds__(256) void k_pre(int* __restrict__ p,
                                             float* __restrict__ m1,
                                             float* __restrict__ outf,
                                             const float* __restrict__ lw,
                                             ushort_t* __restrict__ wh,
                                             ushort_t* __restrict__ wl) {
  int bx = blockIdx.x, t = threadIdx.x;
  if (bx < 65) {
    int i = bx * 256 + t;
    if (i < 16448) p[i] = 0;  // deg[16384] + cnt[64] contiguous
  } else if (bx < 193) {
    m1[(bx - 65) * 256 + t] = 0.f;  // 128*256 = 32768 = 64*512
  } else if (bx == 193) {
    if (t < 128) outf[t] = 0.f;     // final out accumulator (harness poisons 0xAA)
  } else {
    int idx = (bx - 194) * 256 + t;  // < 3*256*256 = 196608
    float v = lw[idx];
    unsigned short h = bf16r(v);
    wh[idx] = h;
    wl[idx] = bf16r(v - __uint_as_float((unsigned)h << 16));
  }
}

// ---------------- deg histogram + cnt (LDS histogram) ----------------
__global__ __launch_bounds__(256) void k_hist(const int* __restrict__ dst,
                                              const int* __restrict__ batch,
                                              int* __restrict__ deg, int* __restrict__ cnt) {
  __shared__ int hist[64];
  int bx = blockIdx.x, t = threadIdx.x;
  if (bx < 512) {
    int e = bx * 256 + t;
    atomicAdd(&deg[dst[e]], 1);
  } else {
    if (t < 64) hist[t] = 0;
    __syncthreads();
    int4 v = ((const int4*)batch)[(bx - 512) * 256 + t];
    int a[4] = {v.x, v.y, v.z, v.w};
    int cur = a[0], run = 1;
#pragma unroll
    for (int j = 1; j < 4; ++j) {
      if (a[j] == cur) run++;
      else { atomicAdd(&hist[cur], run); cur = a[j]; run = 1; }
    }
    atomicAdd(&hist[cur], run);
    __syncthreads();
    if (t < 64 && hist[t]) atomicAdd(&cnt[t], hist[t]);
  }
}

// ---------------- conv layer via MFMA: C = deg*(A@W+b), fused pooling ------
// h stored as SINGLE bf16; A bf16-only => 2 MFMA/tile; W pre-split pair (k_pre).
// SIN=0: A fp32 (x). SIN=1: A bf16 h -> staging = pure copies.
// NOTE r16: cooperative fusion of layers races under graph capture; keep separate.
template <int SIN>
__global__ __launch_bounds__(256, 3) void k_conv(const void* __restrict__ Ap,
                                                 const ushort_t* __restrict__ Wh3,
                                                 const ushort_t* __restrict__ Wl3,
                                                 const float* __restrict__ bias,
                                                 const int* __restrict__ deg,
                                                 ushort_t* __restrict__ Cb,
                                                 float* __restrict__ pooled_p, int lofs) {
  __shared__ __align__(16) unsigned short Ah[64][72];
  __shared__ __align__(16) unsigned short Bh[128][72], Bl[128][72];
  int n0 = blockIdx.x * 128, m0 = blockIdx.y * 64;
  int t = threadIdx.x;
  int w = t >> 6, l = t & 63;
  int wn = w * 32;
  int lr = l & 15, lg = l >> 4;
  f32x4 acc[4][2];
#pragma unroll
  for (int fm = 0; fm < 4; ++fm)
#pragma unroll
    for (int fn = 0; fn < 2; ++fn) acc[fm][fn] = (f32x4){0.f, 0.f, 0.f, 0.f};

  int am = t >> 2, aq = t & 3;
  int bkp = t & 3, bnf = (t >> 2) & 31, brr = t >> 7;

  for (int ks = 0; ks < 4; ++ks) {
    int k0 = ks * 64;
    if (ks) __syncthreads();
    if (SIN == 0) {
      const float* ap = (const float*)Ap + (size_t)(m0 + am) * FF + k0;
#pragma unroll
      for (int i = 0; i < 4; ++i) {
        int k = aq * 4 + i * 16;
        float4 v = *(const float4*)(ap + k);
        unsigned short h0 = bf16r(v.x), h1 = bf16r(v.y), h2 = bf16r(v.z), h3 = bf16r(v.w);
        *(uint2*)&Ah[am][k] = make_uint2((unsigned)h0 | ((unsigned)h1 << 16),
                                         (unsigned)h2 | ((unsigned)h3 << 16));
      }
    } else {
      const ushort_t* ap = (const ushort_t*)Ap + (size_t)(m0 + am) * FF + k0;
#pragma unroll
      for (int i = 0; i < 4; ++i) {
        int k = aq * 4 + i * 16;
        *(uint2*)&Ah[am][k] = *(const uint2*)(ap + k);
      }
    }
#pragma unroll
    for (int r2 = 0; r2 < 4; ++r2) {
      int k = 2 * bkp + 8 * (brr * 4 + r2);
      const ushort_t* whp = Wh3 + (size_t)(k0 + k) * FF + n0 + bnf * 4;
      const ushort_t* wlp = Wl3 + (size_t)(k0 + k) * FF + n0 + bnf * 4;
      uint2 wha = *(const uint2*)whp;
      uint2 whb = *(const uint2*)(whp + FF);
      uint2 wla = *(const uint2*)wlp;
      uint2 wlb = *(const uint2*)(wlp + FF);
      const ushort_t* pha = (const ushort_t*)&wha;
      const ushort_t* phb = (const ushort_t*)&whb;
      const ushort_t* pla = (const ushort_t*)&wla;
      const ushort_t* plb = (const ushort_t*)&wlb;
#pragma unroll
      for (int j = 0; j < 4; ++j) {
        int n = bnf * 4 + j;
        *(unsigned*)&Bh[n][k] = (unsigned)pha[j] | ((unsigned)phb[j] << 16);
        *(unsigned*)&Bl[n][k] = (unsigned)pla[j] | ((unsigned)plb[j] << 16);
      }
    }
    __syncthreads();
#pragma unroll
    for (int k2 = 0; k2 < 2; ++k2) {
      int kk = k2 * 32 + lg * 8;
      short8 afh[4], bfh[2], bfl[2];
#pragma unroll
      for (int fm = 0; fm < 4; ++fm)
        afh[fm] = *(const short8*)&Ah[fm * 16 + lr][kk];
#pragma unroll
      for (int fn = 0; fn < 2; ++fn) {
        bfh[fn] = *(const short8*)&Bh[wn + fn * 16 + lr][kk];
        bfl[fn] = *(const short8*)&Bl[wn + fn * 16 + lr][kk];
      }
#pragma unroll
      for (int fm = 0; fm < 4; ++fm)
#pragma unroll
        for (int fn = 0; fn < 2; ++fn) {
          acc[fm][fn] = __builtin_amdgcn_mfma_f32_16x16x32_bf16(afh[fm], bfl[fn], acc[fm][fn], 0, 0, 0);
          acc[fm][fn] = __builtin_amdgcn_mfma_f32_16x16x32_bf16(afh[fm], bfh[fn], acc[fm][fn], 0, 0, 0);
        }
    }
  }
  float degf[4][4];
#pragma unroll
  for (int fm = 0; fm < 4; ++fm)
#pragma unroll
    for (int r = 0; r < 4; ++r)
      degf[fm][r] = (float)(deg[m0 + fm * 16 + lg * 4 + r] + 1);  // +1 self loop
  int g = blockIdx.y >> 2, sub = blockIdx.y & 3;
#pragma unroll
  for (int fn = 0; fn < 2; ++fn) {
    int col = n0 + wn + fn * 16 + lr;
    float bb = bias[col];
    float cs = 0.f;
#pragma unroll
    for (int fm = 0; fm < 4; ++fm) {
      const float* av = (const float*)&acc[fm][fn];
#pragma unroll
      for (int r = 0; r < 4; ++r) {
        int row = m0 + fm * 16 + lg * 4 + r;
        float v = (av[r] + bb) * degf[fm][r];
        cs += v;
        if (Cb) Cb[(size_t)row * FF + col] = bf16r(v);
      }
    }
    cs += __shfl_xor(cs, 16);
    cs += __shfl_xor(cs, 32);
    if (lg == 0)
      pooled_p[((size_t)sub * 64 + g) * (FF * LL) + lofs + col] = cs;
  }
}

// ---------------- front BN: xt (blocks 0..255, 1024 thr) + pooled (blocks 256..267) ---
__global__ __launch_bounds__(1024, 1) void k_bn_front(const float* __restrict__ x,
                                                      const float* __restrict__ bn_g,
                                                      const float* __restrict__ bn_b,
                                                      const float* __restrict__ pooled_p,
                                                      const int* __restrict__ cnt,
                                                      const float* __restrict__ bnh_g,
                                                      const float* __restrict__ bnh_b,
                                                      ushort_t* __restrict__ zh,
                                                      ushort_t* __restrict__ zl) {
  if (blockIdx.x < 256) {
    __shared__ float sb1[16][256], sb2[16][256];
    __shared__ float rsA[256], bbA[256];
    int i = blockIdx.x, t = threadIdx.x;
    int jq = t & 63, gq = t >> 6;
    int j4 = jq * 4;
    float4 vals[4];
    float s1[4] = {}, s2[4] = {};
#pragma unroll
    for (int r = 0; r < 4; ++r) {
      int g = gq * 4 + r;
      float4 vv = *(const float4*)(x + (size_t)(g * 256 + i) * FF + j4);
      vals[r] = vv;
      s1[0] += vv.x; s2[0] += vv.x * vv.x;
      s1[1] += vv.y; s2[1] += vv.y * vv.y;
      s1[2] += vv.z; s2[2] += vv.z * vv.z;
      s1[3] += vv.w; s2[3] += vv.w * vv.w;
    }
    *(float4*)&sb1[gq][j4] = make_float4(s1[0], s1[1], s1[2], s1[3]);
    *(float4*)&sb2[gq][j4] = make_float4(s2[0], s2[1], s2[2], s2[3]);
    __syncthreads();
    if (t < 256) {
      int j = t;
      float S1 = 0.f, S2 = 0.f;
#pragma unroll
      for (int q = 0; q < 16; ++q) { S1 += sb1[q][j]; S2 += sb2[q][j]; }
      float m = S1 * (1.f / 64.f);
      float var = S2 * (1.f / 64.f) - m * m;
      float rs = 0.f, bb = 0.f;
      if (j > i) {
        int p = i * 255 - (i * (i - 1)) / 2 + (j - i - 1);
        rs = rsqrtf(var + EPSV) * bn_g[p];
        bb = bn_b[p] - m * rs;
      }
      rsA[j] = rs;
      bbA[j] = bb;
    }
    __syncthreads();
    int P0 = i * 255 - (i * (i - 1)) / 2 - i - 1;  // p = P0 + j
#pragma unroll
    for (int r = 0; r < 4; ++r) {
      int g = gq * 4 + r;
      size_t base = (size_t)g * IN1 + P0;
      const float* vf = (const float*)&vals[r];
#pragma unroll
      for (int jj = 0; jj < 4; ++jj) {
        int j = j4 + jj;
        if (j > i) {
          float f = vf[jj] * rsA[j] + bbA[j];
          unsigned short h = bf16r(f);
          zh[base + j] = h;
          zl[base + j] = bf16r(f - __uint_as_float((unsigned)h << 16));
        }
      }
    }
  } else {
    __shared__ float pb1[4][64], pb2[4][64], prs[64], pbb[64];
    int t = threadIdx.x;
    if (t >= 256) return;
    int bx = blockIdx.x - 256;
    int ql = t & 63, gq = t >> 6;
    int q = bx * 64 + ql;
    float vals[16];
    float s1 = 0.f, s2 = 0.f;
#pragma unroll
    for (int gg = 0; gg < 16; ++gg) {
      int g = gq * 16 + gg;
      float v = (pooled_p[((size_t)0 * 64 + g) * (FF * LL) + q] +
                 pooled_p[((size_t)1 * 64 + g) * (FF * LL) + q] +
                 pooled_p[((size_t)2 * 64 + g) * (FF * LL) + q] +
                 pooled_p[((size_t)3 * 64 + g) * (FF * LL) + q]) / (float)cnt[g];
      vals[gg] = v;
      s1 += v;
      s2 += v * v;
    }
    pb1[gq][ql] = s1;
    pb2[gq][ql] = s2;
    __syncthreads();
    if (t < 64) {
      float S1 = pb1[0][t] + pb1[1][t] + pb1[2][t] + pb1[3][t];
      float S2 = pb2[0][t] + pb2[1][t] + pb2[2][t] + pb2[3][t];
      float m = S1 * (1.f / 64.f);
      float var = S2 * (1.f / 64.f) - m * m;
      int qq = bx * 64 + t;
      float rs = rsqrtf(var + EPSV) * bnh_g[qq];
      prs[t] = rs;
      pbb[t] = bnh_b[qq] - m * rs;
    }
    __syncthreads();
#pragma unroll
    for (int gg = 0; gg < 16; ++gg) {
      int g = gq * 16 + gg;
      float f = vals[gg] * prs[ql] + pbb[ql];
      unsigned short h = bf16r(f);
      zh[(size_t)g * IN1 + IU + q] = h;
      zl[(size_t)g * IN1 + IU + q] = bf16r(f - __uint_as_float((unsigned)h << 16));
    }
  }
}

// ---------------- w1 GEMM via MFMA (S=128, 1024 blocks), W rounded to bf16-hi only ---
// m1 feeds batch-BN so w1's bf16 rounding (~2^-9 rel) is within budget; z stays hi/lo.
// 2 MFMA/tile; partials atomicAdd'ed into m1 (zeroed by k_pre). b1 dead (BN cancels).
__global__ __launch_bounds__(256, 4) void k_w1(const ushort_t* __restrict__ zh,
                                               const ushort_t* __restrict__ zl,
                                               const float* __restrict__ W,
                                               float* __restrict__ m1) {
  __shared__ __align__(16) unsigned short Zh[64][72], Zl[64][72];
  __shared__ __align__(16) unsigned short Wh[64][72];
  int nb = blockIdx.x, s = blockIdx.y;
  int t = threadIdx.x;
  int w = t >> 6, l = t & 63, lr = l & 15, lg = l >> 4;
  int ncol = nb * 64 + w * 16 + lr;
  f32x4 acc[4];
#pragma unroll
  for (int mt = 0; mt < 4; ++mt) acc[mt] = (f32x4){0.f, 0.f, 0.f, 0.f};

  for (int c = s; c < 522; c += 128) {  // 33408 = 522*64
    int p0 = c * 64;
    if (c != s) __syncthreads();
#pragma unroll
    for (int it = 0; it < 2; ++it) {
      int idx = it * 256 + t;
      int g = idx >> 3, kq = idx & 7;
      *(uint4*)&Zh[g][kq * 8] = *(const uint4*)(zh + (size_t)g * IN1 + p0 + kq * 8);
      *(uint4*)&Zl[g][kq * 8] = *(const uint4*)(zl + (size_t)g * IN1 + p0 + kq * 8);
    }
#pragma unroll
    for (int it = 0; it < 2; ++it) {
      int idx = it * 256 + t;
      int kp = idx >> 4, cg = idx & 15;
      int k = kp * 2;
      const float* wp = W + (size_t)(p0 + k) * HIDN + nb * 64 + cg * 4;
      float4 va = *(const float4*)wp;
      float4 vb = *(const float4*)(wp + HIDN);
      const float* fa = (const float*)&va;
      const float* fb = (const float*)&vb;
#pragma unroll
      for (int j = 0; j < 4; ++j) {
        unsigned short ha = bf16r(fa[j]);
        unsigned short hb = bf16r(fb[j]);
        int col = cg * 4 + j;
        *(unsigned*)&Wh[col][k] = (unsigned)ha | ((unsigned)hb << 16);
      }
    }
    __syncthreads();
#pragma unroll
    for (int k2 = 0; k2 < 2; ++k2) {
      int kloc = k2 * 32 + lg * 8;
      short8 bh = *(const short8*)&Wh[w * 16 + lr][kloc];
#pragma unroll
      for (int mt = 0; mt < 4; ++mt) {
        short8 ah = *(const short8*)&Zh[mt * 16 + lr][kloc];
        short8 al = *(const short8*)&Zl[mt * 16 + lr][kloc];
        acc[mt] = __builtin_amdgcn_mfma_f32_16x16x32_bf16(al, bh, acc[mt], 0, 0, 0);
        acc[mt] = __builtin_amdgcn_mfma_f32_16x16x32_bf16(ah, bh, acc[mt], 0, 0, 0);
      }
    }
  }
#pragma unroll
  for (int mt = 0; mt < 4; ++mt) {
    const float* av = (const float*)&acc[mt];
#pragma unroll
    for (int r = 0; r < 4; ++r) {
      int g = mt * 16 + lg * 4 + r;
      atomicAdd(&m1[(size_t)g * HIDN + ncol], av[r]);
    }
  }
}

// ---------------- fused small MLP layer(s) -------------------------------------------
// INBN=1: column-BN+ReLU the staged z chunk (bias canceled by BN).
// FIN=1: reduce against w4 (16-lane shfl) and atomicAdd into the 64x2 output;
//        block 0 adds b4. out zeroed by k_pre.
template <int INBN, int FIN>
__global__ __launch_bounds__(256, 2) void k_mlp_small(const float* __restrict__ Z,
                                                      const float* __restrict__ ibn_g,
                                                      const float* __restrict__ ibn_b,
                                                      const float* __restrict__ W,
                                                      const float* __restrict__ gamma,
                                                      const float* __restrict__ beta,
                                                      const float* __restrict__ w4,
                                                      const float* __restrict__ b4,
                                                      float* __restrict__ out, int K, int N) {
  __shared__ float Ws[512 * 16];       // K<=512 rows x 16 cols
  __shared__ float zl[64][132];
  __shared__ float sb1[16][17], sb2[16][17];
  int t = threadIdx.x;
  int h0 = blockIdx.x * 16;
  for (int idx = t; idx < K * 4; idx += 256) {
    int r = idx >> 2, q = idx & 3;
    *(float4*)&Ws[r * 16 + q * 4] = *(const float4*)(W + (size_t)r * N + h0 + q * 4);
  }
  int c = t & 15, gq = t >> 4;         // col c, row-group gq (4 rows each)
  float acc[4] = {};
  for (int ch = 0; ch < K; ch += 128) {
    for (int idx = t; idx < 64 * 32; idx += 256) {
      int g = idx >> 5, kq = idx & 31;
      *(float4*)&zl[g][kq * 4] = *(const float4*)(Z + (size_t)g * K + ch + kq * 4);
    }
    __syncthreads();
    if (INBN) {
      if (t < 128) {
        float s1 = 0.f, s2 = 0.f;
#pragma unroll
        for (int g = 0; g < 64; ++g) {
          float v = zl[g][t];
          s1 += v;
          s2 += v * v;
        }
        float m = s1 * (1.f / 64.f);
        float var = s2 * (1.f / 64.f) - m * m;
        float rs = rsqrtf(var + EPSV) * ibn_g[ch + t];
        float bb = ibn_b[ch + t] - m * rs;
#pragma unroll
        for (int g = 0; g < 64; ++g)
          zl[g][t] = fmaxf(zl[g][t] * rs + bb, 0.f);
      }
      __syncthreads();
    }
#pragma unroll 8
    for (int kk = 0; kk < 128; ++kk) {
      float w = Ws[(ch + kk) * 16 + c];
#pragma unroll
      for (int i = 0; i < 4; ++i) acc[i] = fmaf(zl[gq * 4 + i][kk], w, acc[i]);
    }
    __syncthreads();
  }
  // bias dropped (cancels in the following column-BN)
  float s1 = 0.f, s2 = 0.f;
#pragma unroll
  for (int i = 0; i < 4; ++i) {
    s1 += acc[i];
    s2 += acc[i] * acc[i];
  }
  sb1[gq][c] = s1;
  sb2[gq][c] = s2;
  __syncthreads();
  float S1 = 0.f, S2 = 0.f;
#pragma unroll
  for (int q = 0; q < 16; ++q) { S1 += sb1[q][c]; S2 += sb2[q][c]; }
  float m = S1 * (1.f / 64.f);
  float var = S2 * (1.f / 64.f) - m * m;
  float rs = rsqrtf(var + EPSV) * gamma[h0 + c];
  float be = beta[h0 + c];
  if (!FIN) {
#pragma unroll
    for (int i = 0; i < 4; ++i)
      out[(size_t)(gq * 4 + i) * N + h0 + c] = fmaxf((acc[i] - m) * rs + be, 0.f);
  } else {
    float wa = w4[(h0 + c) * 2 + 0], wb = w4[(h0 + c) * 2 + 1];
    float ca[4], cb[4];
#pragma unroll
    for (int i = 0; i < 4; ++i) {
      float v = fmaxf((acc[i] - m) * rs + be, 0.f);
      ca[i] = v * wa;
      cb[i] = v * wb;
    }
#pragma unroll
    for (int o = 1; o < 16; o <<= 1) {
#pragma unroll
      for (int i = 0; i < 4; ++i) {
        ca[i] += __shfl_xor(ca[i], o);
        cb[i] += __shfl_xor(cb[i], o);
      }
    }
    if (c == 0) {
#pragma unroll
      for (int i = 0; i < 4; ++i) {
        int g = gq * 4 + i;
        atomicAdd(&out[g * 2 + 0], ca[i]);
        atomicAdd(&out[g * 2 + 1], cb[i]);
      }
    }
    if (blockIdx.x == 0 && t < 128) atomicAdd(&out[t], b4[t & 1]);
  }
}

extern "C" void kernel_launch(void* const* d_in, const int* in_sizes, int n_in,
                              void* d_out, int out_size, void* d_ws, size_t ws_size,
                              hipStream_t stream) {
  const float* x = (const float*)d_in[0];
  const int* edge = (const int*)d_in[1];
  const int* batch = (const int*)d_in[2];
  // d_in[3],[4] lin_src_w/b: dead. d_in[7],[8] att_w/b: dead (softmax over singleton = 1).
  // b1/b2/b3 (d_in[14],[18],[22]): dead — per-column constants cancel in batch-BN.
  const float* lin_dst_w = (const float*)d_in[5];
  const float* lin_dst_b = (const float*)d_in[6];
  const float* bn_g = (const float*)d_in[9];
  const float* bn_b = (const float*)d_in[10];
  const float* bnh_g = (const float*)d_in[11];
  const float* bnh_b = (const float*)d_in[12];
  const float* w1 = (const float*)d_in[13];
  const float* g1 = (const float*)d_in[15];
  const float* be1 = (const float*)d_in[16];
  const float* w2 = (const float*)d_in[17];
  const float* g2 = (const float*)d_in[19];
  const float* be2 = (const float*)d_in[20];
  const float* w3 = (const float*)d_in[21];
  const float* g3 = (const float*)d_in[23];
  const float* be3 = (const float*)d_in[24];
  const float* w4 = (const float*)d_in[25];
  const float* b4 = (const float*)d_in[26];
  const int* dstp = edge + EE;  // edge_index[1]

  char* ws = (char*)d_ws;
  int* deg = (int*)(ws);                                     // 64 KB (+cnt adjacent)
  int* cnt = (int*)(ws + 65536);                             // 256 B
  float* bufA = (float*)(ws + 131072);                       // 16 MiB
  float* pooled_p = (float*)(ws + 131072 + 2 * 16777216);    // 786,432 B
  ushort_t* wh3 = (ushort_t*)(ws + 131072 + 2 * 16777216 + 786432);   // 393,216 B
  ushort_t* wl3 = wh3 + (size_t)LL * FF * FF;                          // 393,216 B
  char* tail = ws + 131072 + 2 * 16777216 + 786432 + 786432;
  float* m1 = (float*)(tail);                                // 64x512 (atomic accum)
  float* m2b = (float*)(tail + 131072);                      // 64x256
  // h buffers bf16 (8.4 MB each); zh/zlp reuse bufA after conv3 (h2 dead by then)
  ushort_t* zh = (ushort_t*)bufA;                            // 4.28 MB
  ushort_t* zlp = zh + (size_t)64 * IN1;                     // 4.28 MB
  ushort_t* h1 = (ushort_t*)(ws + 131072 + 16777216);        // bufB region
  ushort_t* h2 = (ushort_t*)(ws + 131072 + 8388608);         // bufA upper half
  float* outf = (float*)d_out;

  k_pre<<<962, 256, 0, stream>>>(deg, m1, outf, lin_dst_w, wh3, wl3);
  k_hist<<<528, 256, 0, stream>>>(dstp, batch, deg, cnt);

  // ---- 3 conv layers (MFMA, A bf16-only -> 2 MFMA/tile, h stored bf16) ----
  k_conv<0><<<dim3(2, 256), 256, 0, stream>>>(x, wh3, wl3, lin_dst_b, deg,
                                              h1, pooled_p, 0);
  k_conv<1><<<dim3(2, 256), 256, 0, stream>>>(h1, wh3 + (size_t)FF * FF,
                                              wl3 + (size_t)FF * FF, lin_dst_b + FF, deg,
                                              h2, pooled_p, FF);
  k_conv<1><<<dim3(2, 256), 256, 0, stream>>>(h2, wh3 + (size_t)2 * FF * FF,
                                              wl3 + (size_t)2 * FF * FF, lin_dst_b + 2 * FF,
                                              deg, (ushort_t*)nullptr, pooled_p, 2 * FF);

  // ---- z = [BN(xt) | BN(sum pooled/cnt)] as bf16 hi/lo ----
  k_bn_front<<<268, 1024, 0, stream>>>(x, bn_g, bn_b, pooled_p, cnt, bnh_g, bnh_b, zh, zlp);

  // ---- MLP: w1 (bf16-hi W, atomic reduce) -> [BN+relu+w2+BN+relu] -> [w3+BN+relu+w4+b4]
  k_w1<<<dim3(8, 128), 256, 0, stream>>>(zh, zlp, w1, m1);
  k_mlp_small<1, 0><<<16, 256, 0, stream>>>(m1, g1, be1, w2, g2, be2,
                                            nullptr, nullptr, m2b, HIDN, 256);
  k_mlp_small<0, 1><<<16, 256, 0, stream>>>(m2b, nullptr, nullptr, w3, g3, be3,
                                            w4, b4, outf, 256, 256);
}

// Round 20
// 156.628 us; speedup vs baseline: 1.0339x; 1.0339x over previous
//
#include <hip/hip_runtime.h>
#include <cstdint>

typedef __attribute__((ext_vector_type(8))) short short8;
typedef __attribute__((ext_vector_type(4))) float f32x4;
typedef unsigned short ushort_t;

static constexpr int NN = 16384, FF = 256, GG = 64, EE = 131072, LL = 3;
static constexpr int HIDN = 512, IU = 32640, IN1 = 33408;
#define EPSV 1e-5f

__device__ inline unsigned short bf16r(float v) {
  unsigned u = __float_as_uint(v);
  u += 0x7FFFu + ((u >> 16) & 1u);
  return (unsigned short)(u >> 16);
}

// -------- k_pre: zero deg/cnt (0..64) + zero m1 (65..192) + zero out (193) +
//          pre-split conv W (194..961) ----------------------------------------------
__global__ __launch_bounds__(256) void k_pre(int* __restrict__ p,
                                             float* __restrict__ m1,
                                             float* __restrict__ outf,
                                             const float* __restrict__ lw,
                                             ushort_t* __restrict__ wh,
                                             ushort_t* __restrict__ wl) {
  int bx = blockIdx.x, t = threadIdx.x;
  if (bx < 65) {
    int i = bx * 256 + t;
    if (i < 16448) p[i] = 0;  // deg[16384] + cnt[64] contiguous
  } else if (bx < 193) {
    m1[(bx - 65) * 256 + t] = 0.f;  // 128*256 = 32768 = 64*512
  } else if (bx == 193) {
    if (t < 128) outf[t] = 0.f;     // final out accumulator (harness poisons 0xAA)
  } else {
    int idx = (bx - 194) * 256 + t;  // < 3*256*256 = 196608
    float v = lw[idx];
    unsigned short h = bf16r(v);
    wh[idx] = h;
    wl[idx] = bf16r(v - __uint_as_float((unsigned)h << 16));
  }
}

// ---------------- deg histogram + cnt (LDS histogram) ----------------
__global__ __launch_bounds__(256) void k_hist(const int* __restrict__ dst,
                                              const int* __restrict__ batch,
                                              int* __restrict__ deg, int* __restrict__ cnt) {
  __shared__ int hist[64];
  int bx = blockIdx.x, t = threadIdx.x;
  if (bx < 512) {
    int e = bx * 256 + t;
    atomicAdd(&deg[dst[e]], 1);
  } else {
    if (t < 64) hist[t] = 0;
    __syncthreads();
    int4 v = ((const int4*)batch)[(bx - 512) * 256 + t];
    int a[4] = {v.x, v.y, v.z, v.w};
    int cur = a[0], run = 1;
#pragma unroll
    for (int j = 1; j < 4; ++j) {
      if (a[j] == cur) run++;
      else { atomicAdd(&hist[cur], run); cur = a[j]; run = 1; }
    }
    atomicAdd(&hist[cur], run);
    __syncthreads();
    if (t < 64 && hist[t]) atomicAdd(&cnt[t], hist[t]);
  }
}

// ---------------- conv layer via MFMA: C = deg*(A@W+b), fused pooling ------
// h stored as SINGLE bf16; A bf16-only => 2 MFMA/tile; W pre-split pair (k_pre).
// SIN=0: A fp32 (x). SIN=1: A bf16 h -> staging = pure copies.
// NOTE r16: cooperative fusion of layers races under graph capture; keep separate.
template <int SIN>
__global__ __launch_bounds__(256, 3) void k_conv(const void* __restrict__ Ap,
                                                 const ushort_t* __restrict__ Wh3,
                                                 const ushort_t* __restrict__ Wl3,
                                                 const float* __restrict__ bias,
                                                 const int* __restrict__ deg,
                                                 ushort_t* __restrict__ Cb,
                                                 float* __restrict__ pooled_p, int lofs) {
  __shared__ __align__(16) unsigned short Ah[64][72];
  __shared__ __align__(16) unsigned short Bh[128][72], Bl[128][72];
  int n0 = blockIdx.x * 128, m0 = blockIdx.y * 64;
  int t = threadIdx.x;
  int w = t >> 6, l = t & 63;
  int wn = w * 32;
  int lr = l & 15, lg = l >> 4;
  f32x4 acc[4][2];
#pragma unroll
  for (int fm = 0; fm < 4; ++fm)
#pragma unroll
    for (int fn = 0; fn < 2; ++fn) acc[fm][fn] = (f32x4){0.f, 0.f, 0.f, 0.f};

  int am = t >> 2, aq = t & 3;
  int bkp = t & 3, bnf = (t >> 2) & 31, brr = t >> 7;

  for (int ks = 0; ks < 4; ++ks) {
    int k0 = ks * 64;
    if (ks) __syncthreads();
    if (SIN == 0) {
      const float* ap = (const float*)Ap + (size_t)(m0 + am) * FF + k0;
#pragma unroll
      for (int i = 0; i < 4; ++i) {
        int k = aq * 4 + i * 16;
        float4 v = *(const float4*)(ap + k);
        unsigned short h0 = bf16r(v.x), h1 = bf16r(v.y), h2 = bf16r(v.z), h3 = bf16r(v.w);
        *(uint2*)&Ah[am][k] = make_uint2((unsigned)h0 | ((unsigned)h1 << 16),
                                         (unsigned)h2 | ((unsigned)h3 << 16));
      }
    } else {
      const ushort_t* ap = (const ushort_t*)Ap + (size_t)(m0 + am) * FF + k0;
#pragma unroll
      for (int i = 0; i < 4; ++i) {
        int k = aq * 4 + i * 16;
        *(uint2*)&Ah[am][k] = *(const uint2*)(ap + k);
      }
    }
#pragma unroll
    for (int r2 = 0; r2 < 4; ++r2) {
      int k = 2 * bkp + 8 * (brr * 4 + r2);
      const ushort_t* whp = Wh3 + (size_t)(k0 + k) * FF + n0 + bnf * 4;
      const ushort_t* wlp = Wl3 + (size_t)(k0 + k) * FF + n0 + bnf * 4;
      uint2 wha = *(const uint2*)whp;
      uint2 whb = *(const uint2*)(whp + FF);
      uint2 wla = *(const uint2*)wlp;
      uint2 wlb = *(const uint2*)(wlp + FF);
      const ushort_t* pha = (const ushort_t*)&wha;
      const ushort_t* phb = (const ushort_t*)&whb;
      const ushort_t* pla = (const ushort_t*)&wla;
      const ushort_t* plb = (const ushort_t*)&wlb;
#pragma unroll
      for (int j = 0; j < 4; ++j) {
        int n = bnf * 4 + j;
        *(unsigned*)&Bh[n][k] = (unsigned)pha[j] | ((unsigned)phb[j] << 16);
        *(unsigned*)&Bl[n][k] = (unsigned)pla[j] | ((unsigned)plb[j] << 16);
      }
    }
    __syncthreads();
#pragma unroll
    for (int k2 = 0; k2 < 2; ++k2) {
      int kk = k2 * 32 + lg * 8;
      short8 afh[4], bfh[2], bfl[2];
#pragma unroll
      for (int fm = 0; fm < 4; ++fm)
        afh[fm] = *(const short8*)&Ah[fm * 16 + lr][kk];
#pragma unroll
      for (int fn = 0; fn < 2; ++fn) {
        bfh[fn] = *(const short8*)&Bh[wn + fn * 16 + lr][kk];
        bfl[fn] = *(const short8*)&Bl[wn + fn * 16 + lr][kk];
      }
#pragma unroll
      for (int fm = 0; fm < 4; ++fm)
#pragma unroll
        for (int fn = 0; fn < 2; ++fn) {
          acc[fm][fn] = __builtin_amdgcn_mfma_f32_16x16x32_bf16(afh[fm], bfl[fn], acc[fm][fn], 0, 0, 0);
          acc[fm][fn] = __builtin_amdgcn_mfma_f32_16x16x32_bf16(afh[fm], bfh[fn], acc[fm][fn], 0, 0, 0);
        }
    }
  }
  float degf[4][4];
#pragma unroll
  for (int fm = 0; fm < 4; ++fm)
#pragma unroll
    for (int r = 0; r < 4; ++r)
      degf[fm][r] = (float)(deg[m0 + fm * 16 + lg * 4 + r] + 1);  // +1 self loop
  int g = blockIdx.y >> 2, sub = blockIdx.y & 3;
#pragma unroll
  for (int fn = 0; fn < 2; ++fn) {
    int col = n0 + wn + fn * 16 + lr;
    float bb = bias[col];
    float cs = 0.f;
#pragma unroll
    for (int fm = 0; fm < 4; ++fm) {
      const float* av = (const float*)&acc[fm][fn];
#pragma unroll
      for (int r = 0; r < 4; ++r) {
        int row = m0 + fm * 16 + lg * 4 + r;
        float v = (av[r] + bb) * degf[fm][r];
        cs += v;
        if (Cb) Cb[(size_t)row * FF + col] = bf16r(v);
      }
    }
    cs += __shfl_xor(cs, 16);
    cs += __shfl_xor(cs, 32);
    if (lg == 0)
      pooled_p[((size_t)sub * 64 + g) * (FF * LL) + lofs + col] = cs;
  }
}

// ---------------- front BN: xt (blocks 0..255, 1024 thr) + pooled (blocks 256..267) ---
__global__ __launch_bounds__(1024, 1) void k_bn_front(const float* __restrict__ x,
                                                      const float* __restrict__ bn_g,
                                                      const float* __restrict__ bn_b,
                                                      const float* __restrict__ pooled_p,
                                                      const int* __restrict__ cnt,
                                                      const float* __restrict__ bnh_g,
                                                      const float* __restrict__ bnh_b,
                                                      ushort_t* __restrict__ zh,
                                                      ushort_t* __restrict__ zl) {
  if (blockIdx.x < 256) {
    __shared__ float sb1[16][256], sb2[16][256];
    __shared__ float rsA[256], bbA[256];
    int i = blockIdx.x, t = threadIdx.x;
    int jq = t & 63, gq = t >> 6;
    int j4 = jq * 4;
    float4 vals[4];
    float s1[4] = {}, s2[4] = {};
#pragma unroll
    for (int r = 0; r < 4; ++r) {
      int g = gq * 4 + r;
      float4 vv = *(const float4*)(x + (size_t)(g * 256 + i) * FF + j4);
      vals[r] = vv;
      s1[0] += vv.x; s2[0] += vv.x * vv.x;
      s1[1] += vv.y; s2[1] += vv.y * vv.y;
      s1[2] += vv.z; s2[2] += vv.z * vv.z;
      s1[3] += vv.w; s2[3] += vv.w * vv.w;
    }
    *(float4*)&sb1[gq][j4] = make_float4(s1[0], s1[1], s1[2], s1[3]);
    *(float4*)&sb2[gq][j4] = make_float4(s2[0], s2[1], s2[2], s2[3]);
    __syncthreads();
    if (t < 256) {
      int j = t;
      float S1 = 0.f, S2 = 0.f;
#pragma unroll
      for (int q = 0; q < 16; ++q) { S1 += sb1[q][j]; S2 += sb2[q][j]; }
      float m = S1 * (1.f / 64.f);
      float var = S2 * (1.f / 64.f) - m * m;
      float rs = 0.f, bb = 0.f;
      if (j > i) {
        int p = i * 255 - (i * (i - 1)) / 2 + (j - i - 1);
        rs = rsqrtf(var + EPSV) * bn_g[p];
        bb = bn_b[p] - m * rs;
      }
      rsA[j] = rs;
      bbA[j] = bb;
    }
    __syncthreads();
    int P0 = i * 255 - (i * (i - 1)) / 2 - i - 1;  // p = P0 + j
#pragma unroll
    for (int r = 0; r < 4; ++r) {
      int g = gq * 4 + r;
      size_t base = (size_t)g * IN1 + P0;
      const float* vf = (const float*)&vals[r];
#pragma unroll
      for (int jj = 0; jj < 4; ++jj) {
        int j = j4 + jj;
        if (j > i) {
          float f = vf[jj] * rsA[j] + bbA[j];
          unsigned short h = bf16r(f);
          zh[base + j] = h;
          zl[base + j] = bf16r(f - __uint_as_float((unsigned)h << 16));
        }
      }
    }
  } else {
    __shared__ float pb1[4][64], pb2[4][64], prs[64], pbb[64];
    int t = threadIdx.x;
    if (t >= 256) return;
    int bx = blockIdx.x - 256;
    int ql = t & 63, gq = t >> 6;
    int q = bx * 64 + ql;
    float vals[16];
    float s1 = 0.f, s2 = 0.f;
#pragma unroll
    for (int gg = 0; gg < 16; ++gg) {
      int g = gq * 16 + gg;
      float v = (pooled_p[((size_t)0 * 64 + g) * (FF * LL) + q] +
                 pooled_p[((size_t)1 * 64 + g) * (FF * LL) + q] +
                 pooled_p[((size_t)2 * 64 + g) * (FF * LL) + q] +
                 pooled_p[((size_t)3 * 64 + g) * (FF * LL) + q]) / (float)cnt[g];
      vals[gg] = v;
      s1 += v;
      s2 += v * v;
    }
    pb1[gq][ql] = s1;
    pb2[gq][ql] = s2;
    __syncthreads();
    if (t < 64) {
      float S1 = pb1[0][t] + pb1[1][t] + pb1[2][t] + pb1[3][t];
      float S2 = pb2[0][t] + pb2[1][t] + pb2[2][t] + pb2[3][t];
      float m = S1 * (1.f / 64.f);
      float var = S2 * (1.f / 64.f) - m * m;
      int qq = bx * 64 + t;
      float rs = rsqrtf(var + EPSV) * bnh_g[qq];
      prs[t] = rs;
      pbb[t] = bnh_b[qq] - m * rs;
    }
    __syncthreads();
#pragma unroll
    for (int gg = 0; gg < 16; ++gg) {
      int g = gq * 16 + gg;
      float f = vals[gg] * prs[ql] + pbb[ql];
      unsigned short h = bf16r(f);
      zh[(size_t)g * IN1 + IU + q] = h;
      zl[(size_t)g * IN1 + IU + q] = bf16r(f - __uint_as_float((unsigned)h << 16));
    }
  }
}

// ---------------- w1 GEMM via MFMA (S=64), partials atomicAdd'ed into m1 -------------
// b1 dropped: BN over the batch dim follows, so a per-column constant cancels.
__global__ __launch_bounds__(256, 4) void k_w1(const ushort_t* __restrict__ zh,
                                               const ushort_t* __restrict__ zl,
                                               const float* __restrict__ W,
                                               float* __restrict__ m1) {
  __shared__ __align__(16) unsigned short Zh[64][72], Zl[64][72];
  __shared__ __align__(16) unsigned short Wh[64][72], Wl[64][72];
  int nb = blockIdx.x, s = blockIdx.y;
  int t = threadIdx.x;
  int w = t >> 6, l = t & 63, lr = l & 15, lg = l >> 4;
  int ncol = nb * 64 + w * 16 + lr;
  f32x4 acc[4];
#pragma unroll
  for (int mt = 0; mt < 4; ++mt) acc[mt] = (f32x4){0.f, 0.f, 0.f, 0.f};

  for (int c = s; c < 522; c += 64) {  // 33408 = 522*64
    int p0 = c * 64;
    if (c != s) __syncthreads();
#pragma unroll
    for (int it = 0; it < 2; ++it) {
      int idx = it * 256 + t;
      int g = idx >> 3, kq = idx & 7;
      *(uint4*)&Zh[g][kq * 8] = *(const uint4*)(zh + (size_t)g * IN1 + p0 + kq * 8);
      *(uint4*)&Zl[g][kq * 8] = *(const uint4*)(zl + (size_t)g * IN1 + p0 + kq * 8);
    }
#pragma unroll
    for (int it = 0; it < 2; ++it) {
      int idx = it * 256 + t;
      int kp = idx >> 4, cg = idx & 15;
      int k = kp * 2;
      const float* wp = W + (size_t)(p0 + k) * HIDN + nb * 64 + cg * 4;
      float4 va = *(const float4*)wp;
      float4 vb = *(const float4*)(wp + HIDN);
      const float* fa = (const float*)&va;
      const float* fb = (const float*)&vb;
#pragma unroll
      for (int j = 0; j < 4; ++j) {
        unsigned ua = __float_as_uint(fa[j]);
        unsigned ub = __float_as_uint(fb[j]);
        unsigned short ha = (unsigned short)(ua >> 16);
        unsigned short hb = (unsigned short)(ub >> 16);
        unsigned short la = bf16r(fa[j] - __uint_as_float(ua & 0xFFFF0000u));
        unsigned short lb = bf16r(fb[j] - __uint_as_float(ub & 0xFFFF0000u));
        int col = cg * 4 + j;
        *(unsigned*)&Wh[col][k] = (unsigned)ha | ((unsigned)hb << 16);
        *(unsigned*)&Wl[col][k] = (unsigned)la | ((unsigned)lb << 16);
      }
    }
    __syncthreads();
#pragma unroll
    for (int k2 = 0; k2 < 2; ++k2) {
      int kloc = k2 * 32 + lg * 8;
      short8 bh = *(const short8*)&Wh[w * 16 + lr][kloc];
      short8 bl = *(const short8*)&Wl[w * 16 + lr][kloc];
#pragma unroll
      for (int mt = 0; mt < 4; ++mt) {
        short8 ah = *(const short8*)&Zh[mt * 16 + lr][kloc];
        short8 al = *(const short8*)&Zl[mt * 16 + lr][kloc];
        acc[mt] = __builtin_amdgcn_mfma_f32_16x16x32_bf16(al, bh, acc[mt], 0, 0, 0);
        acc[mt] = __builtin_amdgcn_mfma_f32_16x16x32_bf16(ah, bl, acc[mt], 0, 0, 0);
        acc[mt] = __builtin_amdgcn_mfma_f32_16x16x32_bf16(ah, bh, acc[mt], 0, 0, 0);
      }
    }
  }
#pragma unroll
  for (int mt = 0; mt < 4; ++mt) {
    const float* av = (const float*)&acc[mt];
#pragma unroll
    for (int r = 0; r < 4; ++r) {
      int g = mt * 16 + lg * 4 + r;
      atomicAdd(&m1[(size_t)g * HIDN + ncol], av[r]);
    }
  }
}

// ---------------- fused small MLP layer(s) -------------------------------------------
// INBN=1: column-BN+ReLU the staged z chunk (bias canceled by BN).
// FIN=1: reduce against w4 (16-lane shfl) and atomicAdd into the 64x2 output;
//        block 0 adds b4. out zeroed by k_pre.
template <int INBN, int FIN>
__global__ __launch_bounds__(256, 2) void k_mlp_small(const float* __restrict__ Z,
                                                      const float* __restrict__ ibn_g,
                                                      const float* __restrict__ ibn_b,
                                                      const float* __restrict__ W,
                                                      const float* __restrict__ gamma,
                                                      const float* __restrict__ beta,
                                                      const float* __restrict__ w4,
                                                      const float* __restrict__ b4,
                                                      float* __restrict__ out, int K, int N) {
  __shared__ float Ws[512 * 16];       // K<=512 rows x 16 cols
  __shared__ float zl[64][132];
  __shared__ float sb1[16][17], sb2[16][17];
  int t = threadIdx.x;
  int h0 = blockIdx.x * 16;
  for (int idx = t; idx < K * 4; idx += 256) {
    int r = idx >> 2, q = idx & 3;
    *(float4*)&Ws[r * 16 + q * 4] = *(const float4*)(W + (size_t)r * N + h0 + q * 4);
  }
  int c = t & 15, gq = t >> 4;         // col c, row-group gq (4 rows each)
  float acc[4] = {};
  for (int ch = 0; ch < K; ch += 128) {
    for (int idx = t; idx < 64 * 32; idx += 256) {
      int g = idx >> 5, kq = idx & 31;
      *(float4*)&zl[g][kq * 4] = *(const float4*)(Z + (size_t)g * K + ch + kq * 4);
    }
    __syncthreads();
    if (INBN) {
      if (t < 128) {
        float s1 = 0.f, s2 = 0.f;
#pragma unroll
        for (int g = 0; g < 64; ++g) {
          float v = zl[g][t];
          s1 += v;
          s2 += v * v;
        }
        float m = s1 * (1.f / 64.f);
        float var = s2 * (1.f / 64.f) - m * m;
        float rs = rsqrtf(var + EPSV) * ibn_g[ch + t];
        float bb = ibn_b[ch + t] - m * rs;
#pragma unroll
        for (int g = 0; g < 64; ++g)
          zl[g][t] = fmaxf(zl[g][t] * rs + bb, 0.f);
      }
      __syncthreads();
    }
#pragma unroll 8
    for (int kk = 0; kk < 128; ++kk) {
      float w = Ws[(ch + kk) * 16 + c];
#pragma unroll
      for (int i = 0; i < 4; ++i) acc[i] = fmaf(zl[gq * 4 + i][kk], w, acc[i]);
    }
    __syncthreads();
  }
  // bias dropped (cancels in the following column-BN)
  float s1 = 0.f, s2 = 0.f;
#pragma unroll
  for (int i = 0; i < 4; ++i) {
    s1 += acc[i];
    s2 += acc[i] * acc[i];
  }
  sb1[gq][c] = s1;
  sb2[gq][c] = s2;
  __syncthreads();
  float S1 = 0.f, S2 = 0.f;
#pragma unroll
  for (int q = 0; q < 16; ++q) { S1 += sb1[q][c]; S2 += sb2[q][c]; }
  float m = S1 * (1.f / 64.f);
  float var = S2 * (1.f / 64.f) - m * m;
  float rs = rsqrtf(var + EPSV) * gamma[h0 + c];
  float be = beta[h0 + c];
  if (!FIN) {
#pragma unroll
    for (int i = 0; i < 4; ++i)
      out[(size_t)(gq * 4 + i) * N + h0 + c] = fmaxf((acc[i] - m) * rs + be, 0.f);
  } else {
    float wa = w4[(h0 + c) * 2 + 0], wb = w4[(h0 + c) * 2 + 1];
    float ca[4], cb[4];
#pragma unroll
    for (int i = 0; i < 4; ++i) {
      float v = fmaxf((acc[i] - m) * rs + be, 0.f);
      ca[i] = v * wa;
      cb[i] = v * wb;
    }
#pragma unroll
    for (int o = 1; o < 16; o <<= 1) {
#pragma unroll
      for (int i = 0; i < 4; ++i) {
        ca[i] += __shfl_xor(ca[i], o);
        cb[i] += __shfl_xor(cb[i], o);
      }
    }
    if (c == 0) {
#pragma unroll
      for (int i = 0; i < 4; ++i) {
        int g = gq * 4 + i;
        atomicAdd(&out[g * 2 + 0], ca[i]);
        atomicAdd(&out[g * 2 + 1], cb[i]);
      }
    }
    if (blockIdx.x == 0 && t < 128) atomicAdd(&out[t], b4[t & 1]);
  }
}

extern "C" void kernel_launch(void* const* d_in, const int* in_sizes, int n_in,
                              void* d_out, int out_size, void* d_ws, size_t ws_size,
                              hipStream_t stream) {
  const float* x = (const float*)d_in[0];
  const int* edge = (const int*)d_in[1];
  const int* batch = (const int*)d_in[2];
  // d_in[3],[4] lin_src_w/b: dead. d_in[7],[8] att_w/b: dead (softmax over singleton = 1).
  // b1/b2/b3 (d_in[14],[18],[22]): dead — per-column constants cancel in batch-BN.
  const float* lin_dst_w = (const float*)d_in[5];
  const float* lin_dst_b = (const float*)d_in[6];
  const float* bn_g = (const float*)d_in[9];
  const float* bn_b = (const float*)d_in[10];
  const float* bnh_g = (const float*)d_in[11];
  const float* bnh_b = (const float*)d_in[12];
  const float* w1 = (const float*)d_in[13];
  const float* g1 = (const float*)d_in[15];
  const float* be1 = (const float*)d_in[16];
  const float* w2 = (const float*)d_in[17];
  const float* g2 = (const float*)d_in[19];
  const float* be2 = (const float*)d_in[20];
  const float* w3 = (const float*)d_in[21];
  const float* g3 = (const float*)d_in[23];
  const float* be3 = (const float*)d_in[24];
  const float* w4 = (const float*)d_in[25];
  const float* b4 = (const float*)d_in[26];
  const int* dstp = edge + EE;  // edge_index[1]

  char* ws = (char*)d_ws;
  int* deg = (int*)(ws);                                     // 64 KB (+cnt adjacent)
  int* cnt = (int*)(ws + 65536);                             // 256 B
  float* bufA = (float*)(ws + 131072);                       // 16 MiB
  float* pooled_p = (float*)(ws + 131072 + 2 * 16777216);    // 786,432 B
  ushort_t* wh3 = (ushort_t*)(ws + 131072 + 2 * 16777216 + 786432);   // 393,216 B
  ushort_t* wl3 = wh3 + (size_t)LL * FF * FF;                          // 393,216 B
  char* tail = ws + 131072 + 2 * 16777216 + 786432 + 786432;
  float* m1 = (float*)(tail);                                // 64x512 (atomic accum)
  float* m2b = (float*)(tail + 131072);                      // 64x256
  // h buffers bf16 (8.4 MB each); zh/zlp reuse bufA after conv3 (h2 dead by then)
  ushort_t* zh = (ushort_t*)bufA;                            // 4.28 MB
  ushort_t* zlp = zh + (size_t)64 * IN1;                     // 4.28 MB
  ushort_t* h1 = (ushort_t*)(ws + 131072 + 16777216);        // bufB region
  ushort_t* h2 = (ushort_t*)(ws + 131072 + 8388608);         // bufA upper half
  float* outf = (float*)d_out;

  k_pre<<<962, 256, 0, stream>>>(deg, m1, outf, lin_dst_w, wh3, wl3);
  k_hist<<<528, 256, 0, stream>>>(dstp, batch, deg, cnt);

  // ---- 3 conv layers (MFMA, A bf16-only -> 2 MFMA/tile, h stored bf16) ----
  k_conv<0><<<dim3(2, 256), 256, 0, stream>>>(x, wh3, wl3, lin_dst_b, deg,
                                              h1, pooled_p, 0);
  k_conv<1><<<dim3(2, 256), 256, 0, stream>>>(h1, wh3 + (size_t)FF * FF,
                                              wl3 + (size_t)FF * FF, lin_dst_b + FF, deg,
                                              h2, pooled_p, FF);
  k_conv<1><<<dim3(2, 256), 256, 0, stream>>>(h2, wh3 + (size_t)2 * FF * FF,
                                              wl3 + (size_t)2 * FF * FF, lin_dst_b + 2 * FF,
                                              deg, (ushort_t*)nullptr, pooled_p, 2 * FF);

  // ---- z = [BN(xt) | BN(sum pooled/cnt)] as bf16 hi/lo ----
  k_bn_front<<<268, 1024, 0, stream>>>(x, bn_g, bn_b, pooled_p, cnt, bnh_g, bnh_b, zh, zlp);

  // ---- MLP: w1 (atomic reduce into m1) -> [BN+relu+w2+BN+relu] -> [w3+BN+relu+w4+b4] --
  k_w1<<<dim3(8, 64), 256, 0, stream>>>(zh, zlp, w1, m1);
  k_mlp_small<1, 0><<<16, 256, 0, stream>>>(m1, g1, be1, w2, g2, be2,
                                            nullptr, nullptr, m2b, HIDN, 256);
  k_mlp_small<0, 1><<<16, 256, 0, stream>>>(m2b, nullptr, nullptr, w3, g3, be3,
                                            w4, b4, outf, 256, 256);
}